// Round 3
// baseline (1082.216 us; speedup 1.0000x reference)
//
#include <hip/hip_runtime.h>
#include <hip/hip_bf16.h>
#include <cstdint>

#define S_LEN 1024
#define DMODEL 1024
#define NHEADS 16
#define DHEAD 64
#define MAXLEN 16384
#define BATCH 4

// ---------------- Projection GEMM: Out(M=4096,N=1024) = X(4096,1024) @ W(1024,1024) + bias
// 64x64 tile, 256 threads, 4x4 micro-tile per thread, KT=16.
__global__ __launch_bounds__(256) void proj_gemm(const float* __restrict__ X,
    const float* __restrict__ W, const float* __restrict__ bias, float* __restrict__ Out) {
  __shared__ float As[16][68];  // [k][m], pad 68 keeps float4 alignment + conflict-free
  __shared__ float Bs[16][68];  // [k][n]
  const int tid = threadIdx.x;
  const int bm = blockIdx.y * 64, bn = blockIdx.x * 64;
  const int tx = tid & 15, ty = tid >> 4;
  float acc[4][4] = {};
  for (int k0 = 0; k0 < DMODEL; k0 += 16) {
#pragma unroll
    for (int i = 0; i < 4; ++i) {
      int idx = tid + i * 256;
      int m = idx >> 4, kk = idx & 15;
      As[kk][m] = X[(size_t)(bm + m) * DMODEL + k0 + kk];
      int n = idx & 63, k2 = idx >> 6;
      Bs[k2][n] = W[(size_t)(k0 + k2) * DMODEL + bn + n];
    }
    __syncthreads();
#pragma unroll
    for (int kk = 0; kk < 16; ++kk) {
      float4 a4 = *(const float4*)&As[kk][ty * 4];
      float4 b4 = *(const float4*)&Bs[kk][tx * 4];
      const float av[4] = {a4.x, a4.y, a4.z, a4.w};
      const float bv[4] = {b4.x, b4.y, b4.z, b4.w};
#pragma unroll
      for (int i = 0; i < 4; ++i)
#pragma unroll
        for (int j = 0; j < 4; ++j) acc[i][j] += av[i] * bv[j];
    }
    __syncthreads();
  }
#pragma unroll
  for (int i = 0; i < 4; ++i) {
    int m = bm + ty * 4 + i;
    int n = bn + tx * 4;
    float4 w;
    w.x = acc[i][0] + bias[n + 0];
    w.y = acc[i][1] + bias[n + 1];
    w.z = acc[i][2] + bias[n + 2];
    w.w = acc[i][3] + bias[n + 3];
    *(float4*)&Out[(size_t)m * DMODEL + n] = w;
  }
}

// ---------------- QEr GEMM: per (b,h): G[s][c] = sum_d q[b,h,s,d] * Er_sl[c][d]
// q stored as proj layout: qp[(b*S+s)*1024 + h*64 + d]. Er_sl row c = Er[(MAXLEN-S+c)*64 + d].
// bh = bh0 + blockIdx.z (global); G is indexed by LOCAL chunk slot blockIdx.z.
__global__ __launch_bounds__(256) void qer_gemm(const float* __restrict__ qp,
    const float* __restrict__ Er, float* __restrict__ G, int bh0) {
  const int bh = bh0 + blockIdx.z;
  const int b = bh >> 4, h = bh & 15;
  const float* A = qp + (size_t)b * S_LEN * DMODEL + h * DHEAD;  // A[s*1024 + d]
  const float* E = Er + (size_t)(MAXLEN - S_LEN) * DHEAD;        // E[c*64 + d]
  float* C = G + (size_t)blockIdx.z * S_LEN * S_LEN;
  const int bm = blockIdx.y * 64, bn = blockIdx.x * 64;
  __shared__ float AsT[64][68];  // [d][s]
  __shared__ float EsT[64][68];  // [d][c]
  const int tid = threadIdx.x;
#pragma unroll
  for (int i = 0; i < 16; ++i) {
    int idx = tid + i * 256;
    int r = idx >> 6, d = idx & 63;
    AsT[d][r] = A[(size_t)(bm + r) * DMODEL + d];
    EsT[d][r] = E[(size_t)(bn + r) * DHEAD + d];
  }
  __syncthreads();
  const int tx = tid & 15, ty = tid >> 4;
  float acc[4][4] = {};
#pragma unroll 8
  for (int d = 0; d < 64; ++d) {
    float4 a4 = *(const float4*)&AsT[d][ty * 4];
    float4 e4 = *(const float4*)&EsT[d][tx * 4];
    const float av[4] = {a4.x, a4.y, a4.z, a4.w};
    const float ev[4] = {e4.x, e4.y, e4.z, e4.w};
#pragma unroll
    for (int i = 0; i < 4; ++i)
#pragma unroll
      for (int j = 0; j < 4; ++j) acc[i][j] += av[i] * ev[j];
  }
#pragma unroll
  for (int i = 0; i < 4; ++i) {
    float4 w;
    w.x = acc[i][0]; w.y = acc[i][1]; w.z = acc[i][2]; w.w = acc[i][3];
    *(float4*)&C[(size_t)(bm + ty * 4 + i) * S_LEN + bn + tx * 4] = w;
  }
}

// ---------------- Fused attention: per (bh, 64-row q-tile), flash-style online softmax.
// score[s][t] = (q_s . k_t + srel(s,t)) / 8, srel read from precomputed G with skew remap:
//   d = t-s:  d<=0 -> G[s][S-1+d];  d==1 -> 0;  d>=2 -> G[s+1][d-2]
// bh = bh0 + blockIdx.y (global); G indexed by LOCAL chunk slot blockIdx.y.
__global__ __launch_bounds__(256) void attn_kernel(const float* __restrict__ qp,
    const float* __restrict__ kp, const float* __restrict__ vp,
    const float* __restrict__ G, float* __restrict__ out, int bh0) {
  const int bh = bh0 + blockIdx.y;
  const int b = bh >> 4, h = bh & 15;
  const int s0 = blockIdx.x * 64;
  __shared__ float Qs[64][68];
  __shared__ float Ks[64][68];
  __shared__ float Vs[64][68];
  __shared__ float Ps[64][68];
  __shared__ float rowm[64], rowl[64], tred[64], sc[64];
  const float* qb = qp + (size_t)b * S_LEN * DMODEL + h * DHEAD;
  const float* kb = kp + (size_t)b * S_LEN * DMODEL + h * DHEAD;
  const float* vb = vp + (size_t)b * S_LEN * DMODEL + h * DHEAD;
  const float* Gb = G + (size_t)blockIdx.y * S_LEN * S_LEN;
  const int tid = threadIdx.x;
#pragma unroll
  for (int i = 0; i < 16; ++i) {
    int idx = tid + i * 256;
    int r = idx >> 6, d = idx & 63;
    Qs[r][d] = qb[(size_t)(s0 + r) * DMODEL + d];
  }
  if (tid < 64) { rowm[tid] = -1e30f; rowl[tid] = 0.f; }
  float4 o0 = {0.f,0.f,0.f,0.f}, o1 = {0.f,0.f,0.f,0.f};
  float4 o2 = {0.f,0.f,0.f,0.f}, o3 = {0.f,0.f,0.f,0.f};
  const int tx = tid & 15, ty = tid >> 4;
  const int rg = tid & 3, r2 = tid >> 2;

  for (int t0 = 0; t0 < S_LEN; t0 += 64) {
    __syncthreads();  // previous iteration's PV reads of Ps/Vs done; Qs ready (iter 0)
#pragma unroll
    for (int i = 0; i < 16; ++i) {
      int idx = tid + i * 256;
      int r = idx >> 6, d = idx & 63;
      Ks[r][d] = kb[(size_t)(t0 + r) * DMODEL + d];
      Vs[r][d] = vb[(size_t)(t0 + r) * DMODEL + d];
    }
    __syncthreads();
    // --- QK^T 4x4 micro-tile
    float accs[4][4] = {};
#pragma unroll
    for (int d4 = 0; d4 < 16; ++d4) {
      float4 q4[4], k4[4];
#pragma unroll
      for (int i = 0; i < 4; ++i) q4[i] = *(const float4*)&Qs[ty * 4 + i][d4 * 4];
#pragma unroll
      for (int j = 0; j < 4; ++j) k4[j] = *(const float4*)&Ks[tx * 4 + j][d4 * 4];
#pragma unroll
      for (int i = 0; i < 4; ++i)
#pragma unroll
        for (int j = 0; j < 4; ++j)
          accs[i][j] += q4[i].x * k4[j].x + q4[i].y * k4[j].y
                      + q4[i].z * k4[j].z + q4[i].w * k4[j].w;
    }
    // --- add skewed rel term, scale, track per-row tile max
    float pm[4] = {-1e30f, -1e30f, -1e30f, -1e30f};
#pragma unroll
    for (int i = 0; i < 4; ++i) {
      int sg = s0 + ty * 4 + i;
#pragma unroll
      for (int j = 0; j < 4; ++j) {
        int tg = t0 + tx * 4 + j;
        int d = tg - sg;
        // Always-in-bounds address; d==1 masked to 0 after load.
        int srow, scol;
        if (d <= 0) { srow = sg; scol = S_LEN - 1 + d; }
        else        { srow = (sg + 1 < S_LEN) ? sg + 1 : S_LEN - 1; scol = (d >= 2) ? d - 2 : 0; }
        float rel = Gb[(size_t)srow * S_LEN + scol];
        if (d == 1) rel = 0.f;
        float sv = (accs[i][j] + rel) * 0.125f;
        accs[i][j] = sv;
        pm[i] = fmaxf(pm[i], sv);
      }
    }
#pragma unroll
    for (int off = 1; off < 16; off <<= 1)
#pragma unroll
      for (int i = 0; i < 4; ++i) pm[i] = fmaxf(pm[i], __shfl_xor(pm[i], off));
    if (tx == 0) {
#pragma unroll
      for (int i = 0; i < 4; ++i) tred[ty * 4 + i] = pm[i];
    }
    __syncthreads();
    if (tid < 64) {
      float mo = rowm[tid];
      float mn = fmaxf(mo, tred[tid]);
      rowm[tid] = mn;
      sc[tid] = __expf(mo - mn);
    }
    __syncthreads();
    // --- p = exp(s - m), write P tile, per-row tile sum
    float psum[4] = {0.f, 0.f, 0.f, 0.f};
#pragma unroll
    for (int i = 0; i < 4; ++i) {
      int r = ty * 4 + i;
      float mn = rowm[r];
#pragma unroll
      for (int j = 0; j < 4; ++j) {
        float p = __expf(accs[i][j] - mn);
        Ps[r][tx * 4 + j] = p;
        psum[i] += p;
      }
    }
#pragma unroll
    for (int off = 1; off < 16; off <<= 1)
#pragma unroll
      for (int i = 0; i < 4; ++i) psum[i] += __shfl_xor(psum[i], off);
    if (tx == 0) {
#pragma unroll
      for (int i = 0; i < 4; ++i) tred[ty * 4 + i] = psum[i];
    }
    __syncthreads();
    if (tid < 64) rowl[tid] = rowl[tid] * sc[tid] + tred[tid];
    // --- rescale O and accumulate PV; 4 threads per row, 16 dh each
    float scl = sc[r2];
    o0.x *= scl; o0.y *= scl; o0.z *= scl; o0.w *= scl;
    o1.x *= scl; o1.y *= scl; o1.z *= scl; o1.w *= scl;
    o2.x *= scl; o2.y *= scl; o2.z *= scl; o2.w *= scl;
    o3.x *= scl; o3.y *= scl; o3.z *= scl; o3.w *= scl;
#pragma unroll 8
    for (int t = 0; t < 64; ++t) {
      float p = Ps[r2][t];
      const float4* vr = (const float4*)&Vs[t][rg * 16];
      float4 v0 = vr[0], v1 = vr[1], v2 = vr[2], v3 = vr[3];
      o0.x += p * v0.x; o0.y += p * v0.y; o0.z += p * v0.z; o0.w += p * v0.w;
      o1.x += p * v1.x; o1.y += p * v1.y; o1.z += p * v1.z; o1.w += p * v1.w;
      o2.x += p * v2.x; o2.y += p * v2.y; o2.z += p * v2.z; o2.w += p * v2.w;
      o3.x += p * v3.x; o3.y += p * v3.y; o3.z += p * v3.z; o3.w += p * v3.w;
    }
  }
  __syncthreads();
  float inv = 1.f / rowl[r2];
  float* ob = out + (size_t)(b * S_LEN + s0 + r2) * DMODEL + h * DHEAD + rg * 16;
  float4 w0 = {o0.x * inv, o0.y * inv, o0.z * inv, o0.w * inv};
  float4 w1 = {o1.x * inv, o1.y * inv, o1.z * inv, o1.w * inv};
  float4 w2 = {o2.x * inv, o2.y * inv, o2.z * inv, o2.w * inv};
  float4 w3 = {o3.x * inv, o3.y * inv, o3.z * inv, o3.w * inv};
  ((float4*)ob)[0] = w0;
  ((float4*)ob)[1] = w1;
  ((float4*)ob)[2] = w2;
  ((float4*)ob)[3] = w3;
}

extern "C" void kernel_launch(void* const* d_in, const int* in_sizes, int n_in,
                              void* d_out, int out_size, void* d_ws, size_t ws_size,
                              hipStream_t stream) {
  const float* q_in = (const float*)d_in[0];
  const float* k_in = (const float*)d_in[1];
  const float* v_in = (const float*)d_in[2];
  const float* Wq   = (const float*)d_in[3];
  const float* bq   = (const float*)d_in[4];
  const float* Wk   = (const float*)d_in[5];
  const float* bk   = (const float*)d_in[6];
  const float* Wv   = (const float*)d_in[7];
  const float* bv   = (const float*)d_in[8];
  const float* Er   = (const float*)d_in[9];
  float* out = (float*)d_out;

  char* ws = (char*)d_ws;
  const size_t MB = (size_t)1 << 20;
  float* qp = (float*)(ws);                 // 16 MB
  float* kp = (float*)(ws + 16 * MB);       // 16 MB
  float* vp = (float*)(ws + 32 * MB);       // 16 MB
  float* G  = (float*)(ws + 48 * MB);       // chunked: nb * 4 MB

  // Size the G chunk to the workspace we actually have.
  const size_t gavail = (ws_size > 48 * MB) ? (ws_size - 48 * MB) : 0;
  int chunk = (int)(gavail / (4 * MB));
  if (chunk < 1) chunk = 1;           // last-resort assumption: >= 52 MB present
  if (chunk > 64) chunk = 64;

  dim3 blk(256);
  dim3 gproj(DMODEL / 64, (BATCH * S_LEN) / 64);         // (16, 64)
  hipLaunchKernelGGL(proj_gemm, gproj, blk, 0, stream, q_in, Wq, bq, qp);
  hipLaunchKernelGGL(proj_gemm, gproj, blk, 0, stream, k_in, Wk, bk, kp);
  hipLaunchKernelGGL(proj_gemm, gproj, blk, 0, stream, v_in, Wv, bv, vp);

  for (int bh0 = 0; bh0 < BATCH * NHEADS; bh0 += chunk) {
    int nb = BATCH * NHEADS - bh0;
    if (nb > chunk) nb = chunk;
    dim3 gqer(S_LEN / 64, S_LEN / 64, nb);
    hipLaunchKernelGGL(qer_gemm, gqer, blk, 0, stream, qp, Er, G, bh0);
    dim3 gattn(S_LEN / 64, nb);
    hipLaunchKernelGGL(attn_kernel, gattn, blk, 0, stream, qp, kp, vp, G, out, bh0);
  }
}

// Round 4
// 245.674 us; speedup vs baseline: 4.4051x; 4.4051x over previous
//
#include <hip/hip_runtime.h>
#include <hip/hip_bf16.h>
#include <cstdint>

#define S_LEN 1024
#define DMODEL 1024
#define NHEADS 16
#define DHEAD 64
#define MAXLEN 16384
#define BATCH 4

typedef __attribute__((ext_vector_type(8))) short bf16x8;
typedef __attribute__((ext_vector_type(4))) float f32x4;

// RNE f32 -> bf16 bits
__device__ inline unsigned short f2b(float f) {
  unsigned int u = __float_as_uint(f);
  unsigned int r = (u + 0x7FFFu + ((u >> 16) & 1u)) >> 16;
  return (unsigned short)r;
}
__device__ inline float b2f(unsigned short u) {
  return __uint_as_float(((unsigned int)u) << 16);
}

// Swizzled LDS element index for [R][64] bf16 rows (128B): 8 slots of 16B, slot ^= row&7.
// 2-way-max bank aliasing on both ds_read_b128 frag reads and staging writes.
#define LDSWZ(row, slot) (((row) << 6) + (((slot) ^ ((row) & 7)) << 3))

// ---------------- W transpose+convert: WT[n][k] bf16 = W[k][n] f32
__global__ __launch_bounds__(256) void wt_convert(const float* __restrict__ W,
                                                  unsigned short* __restrict__ WT) {
  __shared__ float t[32][33];
  const int bi = blockIdx.y * 32, bj = blockIdx.x * 32;  // bi: k, bj: n
  const int r = threadIdx.x >> 3, c4 = (threadIdx.x & 7) * 4;
  float4 f = *(const float4*)&W[(size_t)(bi + r) * DMODEL + bj + c4];
  t[r][c4] = f.x; t[r][c4 + 1] = f.y; t[r][c4 + 2] = f.z; t[r][c4 + 3] = f.w;
  __syncthreads();
  ushort4 u;
  u.x = f2b(t[c4][r]); u.y = f2b(t[c4 + 1][r]);
  u.z = f2b(t[c4 + 2][r]); u.w = f2b(t[c4 + 3][r]);
  *(ushort4*)&WT[(size_t)(bj + r) * DMODEL + bi + c4] = u;
}

// ---------------- Er slice convert: Erb[c][d] = bf16(Er[MAXLEN-S+c][d]), flat copy
__global__ __launch_bounds__(256) void er_convert(const float* __restrict__ Er,
                                                  unsigned short* __restrict__ Erb) {
  const int i = blockIdx.x * 1024 + threadIdx.x * 4;
  float4 f = *(const float4*)(Er + (size_t)(MAXLEN - S_LEN) * DHEAD + i);
  Erb[i] = f2b(f.x); Erb[i + 1] = f2b(f.y); Erb[i + 2] = f2b(f.z); Erb[i + 3] = f2b(f.w);
}

// ---------------- Projection: Out(bf16)[m][n] = X(f32)@W + bias, via WT[n][k] bf16.
// 128x128 tile, BK=64, 4 waves (2x2 of 64x64), 16x16x32 bf16 MFMA, f32->bf16 fused staging.
__global__ __launch_bounds__(256) void proj_mfma(const float* __restrict__ X,
    const unsigned short* __restrict__ WT, const float* __restrict__ bias,
    unsigned short* __restrict__ Out) {
  __shared__ unsigned short As[128 * 64];
  __shared__ unsigned short Bs[128 * 64];
  const int tid = threadIdx.x;
  const int l = tid & 63, wid = tid >> 6;
  const int bm = blockIdx.y * 128, bn = blockIdx.x * 128;
  const int wr = (wid >> 1) * 64, wc = (wid & 1) * 64;
  f32x4 acc[4][4] = {};
  for (int k0 = 0; k0 < DMODEL; k0 += 64) {
    __syncthreads();
#pragma unroll
    for (int r = 0; r < 4; ++r) {  // A: 128x64 f32->bf16
      int s = r * 256 + tid;
      int row = s >> 3, sl = s & 7;
      const float* src = X + (size_t)(bm + row) * DMODEL + k0 + sl * 8;
      float4 f0 = *(const float4*)src;
      float4 f1 = *(const float4*)(src + 4);
      union { unsigned short h[8]; int4 v; } u;
      u.h[0] = f2b(f0.x); u.h[1] = f2b(f0.y); u.h[2] = f2b(f0.z); u.h[3] = f2b(f0.w);
      u.h[4] = f2b(f1.x); u.h[5] = f2b(f1.y); u.h[6] = f2b(f1.z); u.h[7] = f2b(f1.w);
      *(int4*)&As[LDSWZ(row, sl)] = u.v;
    }
#pragma unroll
    for (int r = 0; r < 4; ++r) {  // B: 128x64 bf16 raw
      int s = r * 256 + tid;
      int row = s >> 3, sl = s & 7;
      int4 v = *(const int4*)(WT + (size_t)(bn + row) * DMODEL + k0 + sl * 8);
      *(int4*)&Bs[LDSWZ(row, sl)] = v;
    }
    __syncthreads();
#pragma unroll
    for (int ks = 0; ks < 2; ++ks) {
      bf16x8 a[4], b[4];
#pragma unroll
      for (int f = 0; f < 4; ++f) {
        int row = wr + f * 16 + (l & 15);
        a[f] = *(const bf16x8*)&As[LDSWZ(row, ks * 4 + (l >> 4))];
        int col = wc + f * 16 + (l & 15);
        b[f] = *(const bf16x8*)&Bs[LDSWZ(col, ks * 4 + (l >> 4))];
      }
#pragma unroll
      for (int i = 0; i < 4; ++i)
#pragma unroll
        for (int j = 0; j < 4; ++j)
          acc[i][j] = __builtin_amdgcn_mfma_f32_16x16x32_bf16(a[i], b[j], acc[i][j], 0, 0, 0);
    }
  }
  // epilogue: + bias, cvt bf16. C-frag: col=l&15, row=(l>>4)*4+e
#pragma unroll
  for (int i = 0; i < 4; ++i) {
    int m = bm + wr + i * 16 + ((l >> 4) << 2);
#pragma unroll
    for (int j = 0; j < 4; ++j) {
      int n = bn + wc + j * 16 + (l & 15);
      float bv = bias[n];
#pragma unroll
      for (int e = 0; e < 4; ++e)
        Out[(size_t)(m + e) * DMODEL + n] = f2b(acc[i][j][e] + bv);
    }
  }
}

// ---------------- QEr: G(bf16)[s][c] = q . Er[c], per (b,h). M=N=1024, K=64 single stage.
__global__ __launch_bounds__(256) void qer_mfma(const unsigned short* __restrict__ qp,
    const unsigned short* __restrict__ Erb, unsigned short* __restrict__ G, int bh0) {
  const int bh = bh0 + blockIdx.z;
  const int b = bh >> 4, h = bh & 15;
  __shared__ unsigned short As[128 * 64];
  __shared__ unsigned short Bs[128 * 64];
  const int tid = threadIdx.x, l = tid & 63, wid = tid >> 6;
  const int bm = blockIdx.y * 128, bn = blockIdx.x * 128;
  const int wr = (wid >> 1) * 64, wc = (wid & 1) * 64;
  const unsigned short* qb = qp + (size_t)b * S_LEN * DMODEL + h * DHEAD;
  unsigned short* Gc = G + (size_t)blockIdx.z * S_LEN * S_LEN;
#pragma unroll
  for (int r = 0; r < 4; ++r) {
    int s = r * 256 + tid;
    int row = s >> 3, sl = s & 7;
    *(int4*)&As[LDSWZ(row, sl)] = *(const int4*)(qb + (size_t)(bm + row) * DMODEL + sl * 8);
    *(int4*)&Bs[LDSWZ(row, sl)] = *(const int4*)(Erb + (size_t)(bn + row) * DHEAD + sl * 8);
  }
  __syncthreads();
  f32x4 acc[4][4] = {};
#pragma unroll
  for (int ks = 0; ks < 2; ++ks) {
    bf16x8 a[4], b[4];
#pragma unroll
    for (int f = 0; f < 4; ++f) {
      int row = wr + f * 16 + (l & 15);
      a[f] = *(const bf16x8*)&As[LDSWZ(row, ks * 4 + (l >> 4))];
      int col = wc + f * 16 + (l & 15);
      b[f] = *(const bf16x8*)&Bs[LDSWZ(col, ks * 4 + (l >> 4))];
    }
#pragma unroll
    for (int i = 0; i < 4; ++i)
#pragma unroll
      for (int j = 0; j < 4; ++j)
        acc[i][j] = __builtin_amdgcn_mfma_f32_16x16x32_bf16(a[i], b[j], acc[i][j], 0, 0, 0);
  }
#pragma unroll
  for (int i = 0; i < 4; ++i) {
    int m = bm + wr + i * 16 + ((l >> 4) << 2);
#pragma unroll
    for (int j = 0; j < 4; ++j) {
      int n = bn + wc + j * 16 + (l & 15);
#pragma unroll
      for (int e = 0; e < 4; ++e)
        Gc[(size_t)(m + e) * S_LEN + n] = f2b(acc[i][j][e]);
    }
  }
}

// ---------------- Fused attention, MFMA. Block: 64 q-rows, 4 waves x 16 rows.
// Per t-tile: QK (8 MFMA/wave) -> +rel(G, skew) -> online softmax -> PV (8 MFMA/wave).
__global__ __launch_bounds__(256) void attn_mfma(const unsigned short* __restrict__ qp,
    const unsigned short* __restrict__ kp, const unsigned short* __restrict__ vp,
    const unsigned short* __restrict__ G, float* __restrict__ out, int bh0) {
  const int bh = bh0 + blockIdx.y;
  const int b = bh >> 4, h = bh & 15;
  const int s0 = blockIdx.x * 64;
  __shared__ unsigned short Qs[64 * 64];
  __shared__ unsigned short Ks[64 * 64];
  __shared__ unsigned short Vt[64 * 64];   // [dh][t], swizzled
  __shared__ unsigned short Ps[4][16 * 64];
  const int tid = threadIdx.x, l = tid & 63, w = tid >> 6;
  const int lg = l >> 4, li = l & 15;
  const unsigned short* qb = qp + (size_t)b * S_LEN * DMODEL + h * DHEAD;
  const unsigned short* kb = kp + (size_t)b * S_LEN * DMODEL + h * DHEAD;
  const unsigned short* vb = vp + (size_t)b * S_LEN * DMODEL + h * DHEAD;
  const unsigned short* Gb = G + (size_t)blockIdx.y * S_LEN * S_LEN;

#pragma unroll
  for (int r = 0; r < 2; ++r) {  // stage Q 64x64
    int s = r * 256 + tid;
    int row = s >> 3, sl = s & 7;
    *(int4*)&Qs[LDSWZ(row, sl)] = *(const int4*)(qb + (size_t)(s0 + row) * DMODEL + sl * 8);
  }
  __syncthreads();
  bf16x8 qf[2];
#pragma unroll
  for (int ks = 0; ks < 2; ++ks)
    qf[ks] = *(const bf16x8*)&Qs[LDSWZ(w * 16 + li, ks * 4 + lg)];

  f32x4 o[4] = {};
  float m_r[4] = {-1e30f, -1e30f, -1e30f, -1e30f};
  float l_r[4] = {0.f, 0.f, 0.f, 0.f};

  for (int t0 = 0; t0 < S_LEN; t0 += 64) {
    __syncthreads();  // protect Ks/Vt from prev iter readers
#pragma unroll
    for (int r = 0; r < 2; ++r) {  // stage K 64x64
      int s = r * 256 + tid;
      int row = s >> 3, sl = s & 7;
      *(int4*)&Ks[LDSWZ(row, sl)] = *(const int4*)(kb + (size_t)(t0 + row) * DMODEL + sl * 8);
    }
    {  // stage V transposed: pairs (t0+2pr, t0+2pr+1), dh block of 8 -> b32 word writes
      int pr = tid & 31, dh0 = (tid >> 5) * 8;
      const unsigned short* v0p = vb + (size_t)(t0 + pr * 2) * DMODEL + dh0;
      union { int4 v; unsigned short hh[8]; } va, vc;
      va.v = *(const int4*)v0p;
      vc.v = *(const int4*)(v0p + DMODEL);
      unsigned int* vtw = (unsigned int*)Vt;
#pragma unroll
      for (int j = 0; j < 8; ++j) {
        int dh = dh0 + j;
        int widx = dh * 32 + (((pr >> 2) ^ (dh & 7)) << 2) + (pr & 3);
        vtw[widx] = (unsigned int)va.hh[j] | ((unsigned int)vc.hh[j] << 16);
      }
    }
    __syncthreads();
    // --- QK^T
    f32x4 sa[4] = {};
#pragma unroll
    for (int ks = 0; ks < 2; ++ks) {
#pragma unroll
      for (int f = 0; f < 4; ++f) {
        bf16x8 kf = *(const bf16x8*)&Ks[LDSWZ(f * 16 + li, ks * 4 + lg)];
        sa[f] = __builtin_amdgcn_mfma_f32_16x16x32_bf16(qf[ks], kf, sa[f], 0, 0, 0);
      }
    }
    // --- rel (skewed G) + scale + tile max
    float tmax[4] = {-1e30f, -1e30f, -1e30f, -1e30f};
#pragma unroll
    for (int f = 0; f < 4; ++f) {
#pragma unroll
      for (int i = 0; i < 4; ++i) {
        int sg = s0 + w * 16 + (lg << 2) + i;
        int tg = t0 + f * 16 + li;
        int d = tg - sg;
        int srow, scol;
        if (d <= 0) { srow = sg; scol = S_LEN - 1 + d; }
        else { srow = (sg + 1 < S_LEN) ? sg + 1 : S_LEN - 1; scol = (d >= 2) ? d - 2 : 0; }
        float rel = b2f(Gb[(size_t)srow * S_LEN + scol]);
        if (d == 1) rel = 0.f;
        float sv = (sa[f][i] + rel) * 0.125f;
        sa[f][i] = sv;
        tmax[i] = fmaxf(tmax[i], sv);
      }
    }
#pragma unroll
    for (int off = 8; off >= 1; off >>= 1)
#pragma unroll
      for (int i = 0; i < 4; ++i) tmax[i] = fmaxf(tmax[i], __shfl_xor(tmax[i], off));
    float scale[4];
#pragma unroll
    for (int i = 0; i < 4; ++i) {
      float mn = fmaxf(m_r[i], tmax[i]);
      scale[i] = __expf(m_r[i] - mn);
      m_r[i] = mn;
    }
    // --- P = exp(s-m), write bf16 strip, row-sums
    float psum[4] = {0.f, 0.f, 0.f, 0.f};
#pragma unroll
    for (int f = 0; f < 4; ++f) {
#pragma unroll
      for (int i = 0; i < 4; ++i) {
        float p = __expf(sa[f][i] - m_r[i]);
        psum[i] += p;
        int prow = (lg << 2) + i, pcol = f * 16 + li;
        Ps[w][(prow << 6) + ((((pcol >> 3) ^ (prow & 7)) << 3) + (pcol & 7))] = f2b(p);
      }
    }
#pragma unroll
    for (int off = 8; off >= 1; off >>= 1)
#pragma unroll
      for (int i = 0; i < 4; ++i) psum[i] += __shfl_xor(psum[i], off);
#pragma unroll
    for (int i = 0; i < 4; ++i) l_r[i] = l_r[i] * scale[i] + psum[i];
#pragma unroll
    for (int f = 0; f < 4; ++f)
#pragma unroll
      for (int i = 0; i < 4; ++i) o[f][i] *= scale[i];
    // --- PV
#pragma unroll
    for (int ks = 0; ks < 2; ++ks) {
      bf16x8 pf = *(const bf16x8*)&Ps[w][LDSWZ(li, ks * 4 + lg)];
#pragma unroll
      for (int f = 0; f < 4; ++f) {
        bf16x8 vf = *(const bf16x8*)&Vt[LDSWZ(f * 16 + li, ks * 4 + lg)];
        o[f] = __builtin_amdgcn_mfma_f32_16x16x32_bf16(pf, vf, o[f], 0, 0, 0);
      }
    }
  }
  // epilogue: /l, f32 out
#pragma unroll
  for (int i = 0; i < 4; ++i) {
    float inv = 1.f / l_r[i];
    int sg = s0 + w * 16 + (lg << 2) + i;
#pragma unroll
    for (int f = 0; f < 4; ++f)
      out[(size_t)(b * S_LEN + sg) * DMODEL + h * DHEAD + f * 16 + li] = o[f][i] * inv;
  }
}

extern "C" void kernel_launch(void* const* d_in, const int* in_sizes, int n_in,
                              void* d_out, int out_size, void* d_ws, size_t ws_size,
                              hipStream_t stream) {
  (void)in_sizes; (void)n_in; (void)out_size;
  const float* q_in = (const float*)d_in[0];
  const float* k_in = (const float*)d_in[1];
  const float* v_in = (const float*)d_in[2];
  const float* Wq   = (const float*)d_in[3];
  const float* bq   = (const float*)d_in[4];
  const float* Wk   = (const float*)d_in[5];
  const float* bk   = (const float*)d_in[6];
  const float* Wv   = (const float*)d_in[7];
  const float* bv   = (const float*)d_in[8];
  const float* Er   = (const float*)d_in[9];
  float* out = (float*)d_out;

  char* ws = (char*)d_ws;
  const size_t MB = (size_t)1 << 20;
  unsigned short* wtq = (unsigned short*)(ws);            // 2 MB
  unsigned short* wtk = (unsigned short*)(ws + 2 * MB);   // 2 MB
  unsigned short* wtv = (unsigned short*)(ws + 4 * MB);   // 2 MB
  unsigned short* erb = (unsigned short*)(ws + 6 * MB);   // 128 KB
  unsigned short* qp  = (unsigned short*)(ws + 8 * MB);   // 8 MB
  unsigned short* kp  = (unsigned short*)(ws + 16 * MB);  // 8 MB
  unsigned short* vp  = (unsigned short*)(ws + 24 * MB);  // 8 MB
  unsigned short* G   = (unsigned short*)(ws + 32 * MB);  // nb * 2 MB

  const size_t gavail = (ws_size > 32 * MB) ? (ws_size - 32 * MB) : 0;
  int chunk = (int)(gavail / (2 * MB));
  if (chunk < 1) chunk = 1;
  if (chunk > 64) chunk = 64;

  dim3 blk(256);
  hipLaunchKernelGGL(wt_convert, dim3(32, 32), blk, 0, stream, Wq, wtq);
  hipLaunchKernelGGL(wt_convert, dim3(32, 32), blk, 0, stream, Wk, wtk);
  hipLaunchKernelGGL(wt_convert, dim3(32, 32), blk, 0, stream, Wv, wtv);
  hipLaunchKernelGGL(er_convert, dim3(64), blk, 0, stream, Er, erb);

  dim3 gproj(DMODEL / 128, (BATCH * S_LEN) / 128);  // (8, 32)
  hipLaunchKernelGGL(proj_mfma, gproj, blk, 0, stream, q_in, wtq, bq, qp);
  hipLaunchKernelGGL(proj_mfma, gproj, blk, 0, stream, k_in, wtk, bk, kp);
  hipLaunchKernelGGL(proj_mfma, gproj, blk, 0, stream, v_in, wtv, bv, vp);

  for (int bh0 = 0; bh0 < BATCH * NHEADS; bh0 += chunk) {
    int nb = BATCH * NHEADS - bh0;
    if (nb > chunk) nb = chunk;
    dim3 gqer(S_LEN / 128, S_LEN / 128, nb);  // (8, 8, nb)
    hipLaunchKernelGGL(qer_mfma, gqer, blk, 0, stream, qp, erb, G, bh0);
    dim3 gattn(S_LEN / 64, nb);               // (16, nb)
    hipLaunchKernelGGL(attn_mfma, gattn, blk, 0, stream, qp, kp, vp, G, out, bh0);
  }
}